// Round 10
// baseline (435.513 us; speedup 1.0000x reference)
//
#include <hip/hip_runtime.h>
#include <math.h>

typedef float f2 __attribute__((ext_vector_type(2)));

static constexpr int   B_   = 8;
static constexpr int   N_   = 2048;   // points per set
static constexpr int   TPB  = 512;
static constexpr int   TILE = 32;     // rows/cols owned per block
static constexpr int   BPB  = 64;     // blocks per batch
static constexpr int   NBLK = 512;    // 2 blocks/CU (capacity 4 -> safe margin)
static constexpr int   BN   = B_ * N_;
static constexpr float EPS_ = 1e-9f;
static constexpr float LOG2E = 1.4426950408889634f;

#define SCOPE_A __HIP_MEMORY_SCOPE_AGENT

// ws layout (floats):
//  X1 [4*BN] packed xyz1 (x,y,z,|p|^2)   read-only after init (L2-cached)
//  X2 [4*BN] packed xyz2                 read-only after init
//  LSCAL[BN] LSATR[BN] LWR[BN] WR[BN]    cross-block state (relaxed sc-ops)
//  SLOT [8*64 u32]                       per-block phase slots (barrier)
#define WS_X1    (ws)
#define WS_X2    (ws + 4*BN)
#define WS_LSCAL (ws + 8*BN)
#define WS_LSATR (ws + 9*BN)
#define WS_LWR   (ws + 10*BN)
#define WS_WR    (ws + 11*BN)
#define WS_SLOT  ((unsigned*)(ws + 12*BN))

__device__ __constant__ float c_lvl[11] = {
    -65536.f*LOG2E, -16384.f*LOG2E, -4096.f*LOG2E, -1024.f*LOG2E,
    -256.f*LOG2E,   -64.f*LOG2E,    -16.f*LOG2E,   -4.f*LOG2E,
    -1.f*LOG2E,     -0.25f*LOG2E,   0.f };

__device__ __forceinline__ float aload(const float* p) {
    return __hip_atomic_load(p, __ATOMIC_RELAXED, SCOPE_A);
}
__device__ __forceinline__ void astore(float* p, float v) {
    __hip_atomic_store(p, v, __ATOMIC_RELAXED, SCOPE_A);
}

__global__ void __launch_bounds__(256)
emd_init(const float* __restrict__ xyz1, const float* __restrict__ xyz2,
         float* __restrict__ ws)
{
    const int idx = blockIdx.x * 256 + threadIdx.x;
    if (idx < BN) {
        float x = xyz1[idx*3], y = xyz1[idx*3+1], z = xyz1[idx*3+2];
        reinterpret_cast<float4*>(WS_X1)[idx] =
            make_float4(x, y, z, fmaf(x,x, fmaf(y,y, z*z)));
        x = xyz2[idx*3]; y = xyz2[idx*3+1]; z = xyz2[idx*3+2];
        reinterpret_cast<float4*>(WS_X2)[idx] =
            make_float4(x, y, z, fmaf(x,x, fmaf(y,y, z*z)));
        WS_LSATR[idx] = 0.f;                 // log2(satr=1)
    }
    if (idx < 8 * BPB) WS_SLOT[idx] = 0u;    // re-zero every launch
}

// slot-store barrier: arrival = ONE release store to own slot (no RMW
// contention; wave-0 vmcnt drain covers wave-0 epilogue stores). wait =
// 64 lanes load 64 slots coalesced + __all ballot. No cache invalidates.
__device__ __forceinline__ void bbar(unsigned* slots, int tile, unsigned ph,
                                     int t)
{
    __syncthreads();
    if (t == 0)
        __hip_atomic_store(slots + tile, ph, __ATOMIC_RELEASE, SCOPE_A);
    if (t < 64) {
        int spins = 0;
        for (;;) {
            unsigned v = __hip_atomic_load(slots + t, __ATOMIC_RELAXED, SCOPE_A);
            if (__all(v >= ph)) break;
            __builtin_amdgcn_s_sleep(2);
            if (++spins > (1 << 17)) break;   // fail visibly, never hang
        }
        __builtin_amdgcn_fence(__ATOMIC_ACQUIRE, "workgroup");
    }
    __syncthreads();
}

// block reduction of 8 row-partials -> 32 row sums (valid in t < 32)
// sc = pts overlay (19 KB used); leading sync covers previous readers.
__device__ __forceinline__ float reduce32(float* sc, const float (&s)[8], int t)
{
    const int c = t >> 2, g = t & 3;
    __syncthreads();
#pragma unroll
    for (int j = 0; j < 8; ++j) sc[c*33 + g*8 + j] = s[j];
    __syncthreads();
    const int col = t & 31, seg = t >> 5;    // 16 segs x 32 cols = 512
    float v = 0.f;
#pragma unroll
    for (int k = 0; k < 8; ++k) v += sc[(seg*8 + k)*33 + col];
    sc[4224 + seg*33 + col] = v;             // disjoint region, no sync needed
    __syncthreads();
    float rs = 0.f;
    if (t < 32) {
#pragma unroll
        for (int q = 0; q < 16; ++q) rs += sc[4224 + q*33 + t];
    }
    return rs;
}

// ---- packed sweeps (R9 bodies; l = t>>2, 16 iters, stride 128) ----
__device__ __forceinline__ void sweep01(const float4* pts,
    const f2 (&kx)[4], const f2 (&ky)[4], const f2 (&kz)[4], const f2 (&kc)[4],
    int t, float (&s1)[8])
{
#pragma unroll
    for (int j = 0; j < 8; ++j) s1[j] = 0.f;
    int l = t >> 2;
    float4 p = pts[l];
#pragma unroll 4
    for (int i = 0; i < 16; ++i) {
        const int ln = (l + 128) & (N_ - 1);
        const float4 pn = pts[ln];
        const f2 px = (f2){p.x, p.x}, py = (f2){p.y, p.y}, pz = (f2){p.z, p.z};
        const f2 pw = (f2){p.w, p.w};
#pragma unroll
        for (int jp = 0; jp < 4; ++jp) {
            f2 a = kc[jp] + pw;
            a = kz[jp] * pz + a;
            a = ky[jp] * py + a;
            a = kx[jp] * px + a;
            s1[2*jp]   += __builtin_amdgcn_exp2f(a.x);
            s1[2*jp+1] += __builtin_amdgcn_exp2f(a.y);
        }
        p = pn; l = ln;
    }
}

__device__ __forceinline__ void sweep2(const float4* pts, const float* auxB,
    const f2 (&kx)[4], const f2 (&ky)[4], const f2 (&kz)[4], const f2 (&kc)[4],
    float lvA, float lvB, int t, float (&s1)[8], float (&s2)[8], float (&s3)[8])
{
#pragma unroll
    for (int j = 0; j < 8; ++j) { s1[j] = 0.f; s2[j] = 0.f; s3[j] = 0.f; }
    int l = t >> 2;
    float4 p = pts[l];
    float  ab = auxB[l];
#pragma unroll 2
    for (int i = 0; i < 16; ++i) {
        const int ln = (l + 128) & (N_ - 1);
        const float4 pn = pts[ln];
        const float  abn = auxB[ln];
        const f2 px = (f2){p.x, p.x}, py = (f2){p.y, p.y}, pz = (f2){p.z, p.z};
        const float p2s = fmaf(p.x, p.x, fmaf(p.y, p.y, p.z * p.z));
#pragma unroll
        for (int jp = 0; jp < 4; ++jp) {
            f2 dq = kz[jp] * pz + kc[jp];
            dq = ky[jp] * py + dq;
            dq = kx[jp] * px + dq;                  // |q|^2 - 2 p.q
            const float sq0 = __builtin_amdgcn_sqrtf(fmaxf(dq.x + p2s, 0.f));
            const float sq1 = __builtin_amdgcn_sqrtf(fmaxf(dq.y + p2s, 0.f));
            const float eA0 = __builtin_amdgcn_exp2f(fmaf(lvA, dq.x, p.w));
            const float eA1 = __builtin_amdgcn_exp2f(fmaf(lvA, dq.y, p.w));
            const float eB0 = __builtin_amdgcn_exp2f(fmaf(lvB, dq.x, ab));
            const float eB1 = __builtin_amdgcn_exp2f(fmaf(lvB, dq.y, ab));
            s1[2*jp]   += eA0;            s1[2*jp+1] += eA1;
            s2[2*jp]    = fmaf(eA0, sq0, s2[2*jp]);
            s2[2*jp+1]  = fmaf(eA1, sq1, s2[2*jp+1]);
            s3[2*jp]   += eB0;            s3[2*jp+1] += eB1;
        }
        p = pn; ab = abn; l = ln;
    }
}

__device__ __forceinline__ void sweep3(const float4* pts,
    const f2 (&kx)[4], const f2 (&ky)[4], const f2 (&kz)[4], const f2 (&kc)[4],
    int t, float (&s2)[8])
{
#pragma unroll
    for (int j = 0; j < 8; ++j) s2[j] = 0.f;
    int l = t >> 2;
    float4 p = pts[l];
#pragma unroll 4
    for (int i = 0; i < 16; ++i) {
        const int ln = (l + 128) & (N_ - 1);
        const float4 pn = pts[ln];
        const f2 px = (f2){p.x, p.x}, py = (f2){p.y, p.y}, pz = (f2){p.z, p.z};
        const float p2s = fmaf(p.x, p.x, fmaf(p.y, p.y, p.z * p.z));
#pragma unroll
        for (int jp = 0; jp < 4; ++jp) {
            f2 dq = kz[jp] * pz + kc[jp];
            dq = ky[jp] * py + dq;
            dq = kx[jp] * px + dq;
            const float sq0 = __builtin_amdgcn_sqrtf(fmaxf(dq.x + p2s, 0.f));
            const float sq1 = __builtin_amdgcn_sqrtf(fmaxf(dq.y + p2s, 0.f));
            s2[2*jp]   = fmaf(p.w, sq0, s2[2*jp]);
            s2[2*jp+1] = fmaf(p.w, sq1, s2[2*jp+1]);
        }
        p = pn; l = ln;
    }
}

// load 8 owned points (pair-packed); scaled==true -> k = -2*lv*q, kc = lv*|q|^2
__device__ __forceinline__ void own_coeff(const float4* src, int ob, float lv,
    bool scaled, f2 (&kx)[4], f2 (&ky)[4], f2 (&kz)[4], f2 (&kc)[4])
{
#pragma unroll
    for (int jp = 0; jp < 4; ++jp) {
        float4 v0 = src[ob + 2*jp], v1 = src[ob + 2*jp + 1];
        const float m2 = scaled ? (-2.f * lv) : -2.f;
        const float mc = scaled ? lv : 1.f;
        kx[jp] = (f2){m2*v0.x, m2*v1.x};
        ky[jp] = (f2){m2*v0.y, m2*v1.y};
        kz[jp] = (f2){m2*v0.z, m2*v1.z};
        kc[jp] = (f2){mc*v0.w, mc*v1.w};
    }
}

__global__ void __launch_bounds__(TPB, 4)
emd_main(float* __restrict__ ws, float* __restrict__ out)
{
    __shared__ __align__(16) char smem[40960];
    float4* pts  = reinterpret_cast<float4*>(smem);
    float*  auxB = reinterpret_cast<float*>(smem + 32768);   // M2 only
    float*  sc   = reinterpret_cast<float*>(smem);           // reduce overlay

    const int b    = blockIdx.x & 7;     // batch -> XCD (round-robin dispatch)
    const int tile = blockIdx.x >> 3;    // 0..63
    const int t    = threadIdx.x;

    unsigned* slots = WS_SLOT + b * BPB;
    unsigned  ph = 0;

    const float4* x1v = reinterpret_cast<const float4*>(WS_X1) + b * N_;
    const float4* x2v = reinterpret_cast<const float4*>(WS_X2) + b * N_;
    float* lscal = WS_LSCAL + b * N_;
    float* lsatr = WS_LSATR + b * N_;
    float* lwr   = WS_LWR   + b * N_;
    float* wrp   = WS_WR    + b * N_;

    const int ob = tile * TILE + (t & 3) * 8;   // owned 8 rows/cols
    float satl = 1.f, satr = 1.f, mysc = 0.f, cost = 0.f;   // valid t < 32
    const int gi = tile * TILE + t;             // t<32 epilogue index
    f2 kx[4], ky[4], kz[4], kc[4];
    float s1[8], s2[8], s3[8];

    // ============ M0: level-0 row sweep -> scale ============
    {
        const float lv = c_lvl[0];
        for (int p = t; p < N_; p += TPB) {
            float4 v = x2v[p];
            pts[p] = make_float4(v.x, v.y, v.z, lv * v.w);   // lsatr = 0
        }
        own_coeff(x1v, ob, lv, true, kx, ky, kz, kc);
        __syncthreads();
        sweep01(pts, kx, ky, kz, kc, t, s1);
        const float rs1 = reduce32(sc, s1, t);
        if (t < 32) {
            mysc = satl / (rs1 + EPS_);
            astore(lscal + gi, __log2f(mysc));
        }
        bbar(slots, tile, ++ph, t);
    }

    for (int lev = 0; lev <= 10; ++lev) {
        // ============ M1: col sweep at lev ============
        {
            const float lv = c_lvl[lev];
            for (int p = t; p < N_; p += TPB) {
                float4 v = x1v[p];
                pts[p] = make_float4(v.x, v.y, v.z,
                                     fmaf(lv, v.w, aload(lscal + p)));
            }
            own_coeff(x2v, ob, lv, true, kx, ky, kz, kc);
            __syncthreads();
            sweep01(pts, kx, ky, kz, kc, t, s1);
            const float rs1 = reduce32(sc, s1, t);
            if (t < 32) {
                const float w1s = satr * rs1;
                const float rr  = fminf(satr / (w1s + EPS_), 1.f);
                const float wrv = satr * rr;
                satr = fmaxf(satr - rr * w1s, 0.f);
                astore(wrp   + gi, wrv);
                astore(lwr   + gi, __log2f(wrv));
                astore(lsatr + gi, __log2f(satr));
            }
            bbar(slots, tile, ++ph, t);
        }

        if (lev < 10) {
            // ===== M2: merged P3(lev) + P1(lev+1) row sweep =====
            const float lvA = c_lvl[lev], lvB = c_lvl[lev + 1];
            for (int p = t; p < N_; p += TPB) {
                float4 v = x2v[p];
                pts[p]  = make_float4(v.x, v.y, v.z,
                                      fmaf(lvA, v.w, aload(lwr + p)));
                auxB[p] = fmaf(lvB, v.w, aload(lsatr + p));
            }
            own_coeff(x1v, ob, 0.f, false, kx, ky, kz, kc);
            __syncthreads();
            sweep2(pts, auxB, kx, ky, kz, kc, lvA, lvB, t, s1, s2, s3);
            const float rs1 = reduce32(sc, s1, t);
            const float rs2 = reduce32(sc, s2, t);
            const float rs3 = reduce32(sc, s3, t);
            if (t < 32) {
                satl = fmaxf(satl - mysc * rs1, 0.f);
                cost = fmaf(mysc, rs2, cost);
                mysc = satl / (rs3 + EPS_);
                astore(lscal + gi, __log2f(mysc));
            }
            bbar(slots, tile, ++ph, t);
        } else {
            // ===== M3: final row sweep (lvl = 0 -> weight = raw wr) =====
            for (int p = t; p < N_; p += TPB) {
                float4 v = x2v[p];
                pts[p] = make_float4(v.x, v.y, v.z, aload(wrp + p));
            }
            own_coeff(x1v, ob, 0.f, false, kx, ky, kz, kc);
            __syncthreads();
            sweep3(pts, kx, ky, kz, kc, t, s2);
            const float rs2 = reduce32(sc, s2, t);
            if (t < 32) {
                float v = fmaf(mysc, rs2, cost);
#pragma unroll
                for (int k = 16; k >= 1; k >>= 1) v += __shfl_xor(v, k, 32);
                if (t == 0) atomicAdd(out + b, v);
            }
        }
    }
}

extern "C" void kernel_launch(void* const* d_in, const int* in_sizes, int n_in,
                              void* d_out, int out_size, void* d_ws, size_t ws_size,
                              hipStream_t stream)
{
    const float* xyz1 = (const float*)d_in[0];
    const float* xyz2 = (const float*)d_in[1];
    float* out = (float*)d_out;
    float* ws  = (float*)d_ws;

    hipMemsetAsync(d_out, 0, B_ * sizeof(float), stream);
    emd_init<<<(BN + 255) / 256, 256, 0, stream>>>(xyz1, xyz2, ws);
    emd_main<<<NBLK, TPB, 0, stream>>>(ws, out);
}

// Round 11
// 324.652 us; speedup vs baseline: 1.3415x; 1.3415x over previous
//
#include <hip/hip_runtime.h>
#include <math.h>

typedef float f2 __attribute__((ext_vector_type(2)));

static constexpr int   B_   = 8;
static constexpr int   N_   = 2048;   // points per set
static constexpr int   TPB  = 512;
static constexpr int   TILE = 32;     // rows owned per block
static constexpr int   NBLK = 512;    // 64 tiles x 8 batches
static constexpr int   BN   = B_ * N_;
static constexpr float EPS_ = 1e-9f;
static constexpr float LOG2E = 1.4426950408889634f;

// ws layout (floats):
//  X1 [4*BN] (x,y,z,|p|^2)   X2 [4*BN]
//  SATL[BN] COST[BN] SCAL[BN] (block-owned rows, plain cross-dispatch)
//  SATR0[BN] SATR1[BN]       (level-parity double buffer, owner-block writes)
//  CS [11][BN]               (per-level column sums, atomicAdd-accumulated)
#define WS_X1    (ws)
#define WS_X2    (ws + 4*BN)
#define WS_SATL  (ws + 8*BN)
#define WS_COST  (ws + 9*BN)
#define WS_SCAL  (ws + 10*BN)
#define WS_SATR0 (ws + 11*BN)
#define WS_SATR1 (ws + 12*BN)
#define WS_CS    (ws + 13*BN)

__global__ void __launch_bounds__(256)
emd_init(const float* __restrict__ xyz1, const float* __restrict__ xyz2,
         float* __restrict__ ws)
{
    const int idx = blockIdx.x * 256 + threadIdx.x;
    if (idx >= BN) return;
    float x = xyz1[idx*3], y = xyz1[idx*3+1], z = xyz1[idx*3+2];
    reinterpret_cast<float4*>(WS_X1)[idx] =
        make_float4(x, y, z, fmaf(x,x, fmaf(y,y, z*z)));
    x = xyz2[idx*3]; y = xyz2[idx*3+1]; z = xyz2[idx*3+2];
    reinterpret_cast<float4*>(WS_X2)[idx] =
        make_float4(x, y, z, fmaf(x,x, fmaf(y,y, z*z)));
    WS_SATL[idx]  = 1.f;
    WS_COST[idx]  = 0.f;
    WS_SATR0[idx] = 1.f;
#pragma unroll
    for (int a = 0; a < 11; ++a) (WS_CS + a*BN)[idx] = 0.f;
}

// ---- R10-proven sweep bodies (l = t>>2, 16 iters, stride 128) ----
__device__ __forceinline__ void sweep01(const float4* pts,
    const f2 (&kx)[4], const f2 (&ky)[4], const f2 (&kz)[4], const f2 (&kc)[4],
    int t, float (&s1)[8])
{
#pragma unroll
    for (int j = 0; j < 8; ++j) s1[j] = 0.f;
    int l = t >> 2;
    float4 p = pts[l];
#pragma unroll 4
    for (int i = 0; i < 16; ++i) {
        const int ln = (l + 128) & (N_ - 1);
        const float4 pn = pts[ln];
        const f2 px = (f2){p.x,p.x}, py = (f2){p.y,p.y}, pz = (f2){p.z,p.z};
        const f2 pw = (f2){p.w,p.w};
#pragma unroll
        for (int jp = 0; jp < 4; ++jp) {
            f2 a = kc[jp] + pw;
            a = kz[jp] * pz + a;
            a = ky[jp] * py + a;
            a = kx[jp] * px + a;
            s1[2*jp]   += __builtin_amdgcn_exp2f(a.x);
            s1[2*jp+1] += __builtin_amdgcn_exp2f(a.y);
        }
        p = pn; l = ln;
    }
}

__device__ __forceinline__ void sweepM(const float4* pts, const float* auxB,
    const f2 (&kx)[4], const f2 (&ky)[4], const f2 (&kz)[4], const f2 (&kc)[4],
    float lvA, float lvB, int t, float (&s1)[8], float (&s2)[8], float (&s3)[8])
{
#pragma unroll
    for (int j = 0; j < 8; ++j) { s1[j] = 0.f; s2[j] = 0.f; s3[j] = 0.f; }
    int l = t >> 2;
    float4 p = pts[l];
    float  ab = auxB[l];
#pragma unroll 2
    for (int i = 0; i < 16; ++i) {
        const int ln = (l + 128) & (N_ - 1);
        const float4 pn = pts[ln];
        const float  abn = auxB[ln];
        const f2 px = (f2){p.x,p.x}, py = (f2){p.y,p.y}, pz = (f2){p.z,p.z};
        const float p2s = fmaf(p.x, p.x, fmaf(p.y, p.y, p.z * p.z));
#pragma unroll
        for (int jp = 0; jp < 4; ++jp) {
            f2 dq = kz[jp] * pz + kc[jp];
            dq = ky[jp] * py + dq;
            dq = kx[jp] * px + dq;                  // |q|^2 - 2 p.q
            const float sq0 = __builtin_amdgcn_sqrtf(fmaxf(dq.x + p2s, 0.f));
            const float sq1 = __builtin_amdgcn_sqrtf(fmaxf(dq.y + p2s, 0.f));
            const float eA0 = __builtin_amdgcn_exp2f(fmaf(lvA, dq.x, p.w));
            const float eA1 = __builtin_amdgcn_exp2f(fmaf(lvA, dq.y, p.w));
            const float eB0 = __builtin_amdgcn_exp2f(fmaf(lvB, dq.x, ab));
            const float eB1 = __builtin_amdgcn_exp2f(fmaf(lvB, dq.y, ab));
            s1[2*jp]   += eA0;            s1[2*jp+1] += eA1;
            s2[2*jp]    = fmaf(eA0, sq0, s2[2*jp]);
            s2[2*jp+1]  = fmaf(eA1, sq1, s2[2*jp+1]);
            s3[2*jp]   += eB0;            s3[2*jp+1] += eB1;
        }
        p = pn; ab = abn; l = ln;
    }
}

__device__ __forceinline__ void sweep3(const float4* pts,
    const f2 (&kx)[4], const f2 (&ky)[4], const f2 (&kz)[4],
    int t, float (&s2)[8])
{
#pragma unroll
    for (int j = 0; j < 8; ++j) s2[j] = 0.f;
    int l = t >> 2;
    float4 p = pts[l];
#pragma unroll 4
    for (int i = 0; i < 16; ++i) {
        const int ln = (l + 128) & (N_ - 1);
        const float4 pn = pts[ln];
        const f2 px = (f2){p.x,p.x}, py = (f2){p.y,p.y}, pz = (f2){p.z,p.z};
        const float p2s = fmaf(p.x, p.x, fmaf(p.y, p.y, p.z * p.z));
#pragma unroll
        for (int jp = 0; jp < 4; ++jp) {
            f2 dq = (f2){-2.f,-2.f} * (kx[jp] * px);
            // recompute as standard diff form for exactness with R10 path:
            const float dx0 = p.x - kx[jp].x, dy0 = p.y - ky[jp].x, dz0 = p.z - kz[jp].x;
            const float dx1 = p.x - kx[jp].y, dy1 = p.y - ky[jp].y, dz1 = p.z - kz[jp].y;
            const float d20 = fmaf(dx0,dx0, fmaf(dy0,dy0, dz0*dz0));
            const float d21 = fmaf(dx1,dx1, fmaf(dy1,dy1, dz1*dz1));
            s2[2*jp]   = fmaf(p.w, __builtin_amdgcn_sqrtf(fmaxf(d20, 0.f)), s2[2*jp]);
            s2[2*jp+1] = fmaf(p.w, __builtin_amdgcn_sqrtf(fmaxf(d21, 0.f)), s2[2*jp+1]);
            (void)dq; (void)p2s;
        }
        p = pn; l = ln;
    }
}

// wave-shuffle reduce: sums each of 8 row-partials over the 16 same-rg lanes
// of the wave, then lanes 0..3 of each wave write [row][wave] to aux[a*256..].
__device__ __forceinline__ void wave_reduce8(float (&s)[8], float* aux, int a,
                                             int t)
{
#pragma unroll
    for (int j = 0; j < 8; ++j) {
        float v = s[j];
        v += __shfl_xor(v, 4, 64);
        v += __shfl_xor(v, 8, 64);
        v += __shfl_xor(v, 16, 64);
        v += __shfl_xor(v, 32, 64);
        s[j] = v;
    }
    if ((t & 63) < 4) {
        const int w = t >> 6;
#pragma unroll
        for (int j = 0; j < 8; ++j)
            aux[a*256 + ((t & 3)*8 + j)*8 + w] = s[j];
    }
}

// MODE 0: level-0 row sweep -> scale(0), colpartial cs(0)
// MODE 1: P3(lev) + P1(lev+1) row sweep + colpartial cs(lev+1); wr/satr inline
// MODE 2: final P3 at level 10 (weight = wr inline) -> cost -> out
template<int MODE>
__global__ void __launch_bounds__(TPB, 4)
emd_fused(float* __restrict__ ws, float* __restrict__ out,
          const float lvA, const float lvB, const int lev)
{
    __shared__ __align__(16) float4 pts[N_];   // 32 KB
    __shared__ float aux[N_];                  // 8 KB: staged arg / reduce / bcast

    const int b    = blockIdx.x & 7;
    const int tile = blockIdx.x >> 3;
    const int t    = threadIdx.x;
    const int rg   = t & 3;

    const float4* x1v = reinterpret_cast<const float4*>(WS_X1) + b * N_;
    const float4* x2v = reinterpret_cast<const float4*>(WS_X2) + b * N_;
    float* satl = WS_SATL + b * N_;
    float* cost = WS_COST + b * N_;
    float* scal = WS_SCAL + b * N_;
    const float* satrC = ((lev & 1) ? WS_SATR1 : WS_SATR0) + b * N_;
    float*       satrN = ((lev & 1) ? WS_SATR0 : WS_SATR1) + b * N_;
    const float* csC = WS_CS + (size_t)lev * BN + b * N_;
    float* csN = WS_CS + (size_t)((MODE == 0) ? 0 : lev + 1) * BN + b * N_;

    // ---- staging (wr/satr_next computed inline from satr + colsum) ----
    for (int p = t; p < N_; p += TPB) {
        float4 v = x2v[p];
        if (MODE == 0) {
            pts[p] = make_float4(v.x, v.y, v.z, lvB * v.w);   // lsatr(0)=0
        } else {
            const float sr  = satrC[p];
            const float cs  = csC[p];
            const float ss  = fmaf(sr, cs, EPS_);
            const float rr  = fminf(sr / ss, 1.f);
            const float wrv = sr * rr;
            if (MODE == 1) {
                const float sn = fmaxf(sr - rr * sr * cs, 0.f);
                pts[p] = make_float4(v.x, v.y, v.z,
                                     fmaf(lvA, v.w, __log2f(wrv)));
                aux[p] = fmaf(lvB, v.w, __log2f(sn));
                if ((p >> 5) == tile) satrN[p] = sn;   // owner writes next parity
            } else {
                pts[p] = make_float4(v.x, v.y, v.z, wrv);
            }
        }
    }

    // owned rows (set 1) coefficients for sweep 1
    const int ob = tile * TILE + rg * 8;
    f2 kx[4], ky[4], kz[4], kc[4];
#pragma unroll
    for (int jp = 0; jp < 4; ++jp) {
        float4 v0 = x1v[ob + 2*jp], v1 = x1v[ob + 2*jp + 1];
        if (MODE == 0) {
            const float m2 = -2.f * lvB;
            kx[jp] = (f2){m2*v0.x, m2*v1.x};
            ky[jp] = (f2){m2*v0.y, m2*v1.y};
            kz[jp] = (f2){m2*v0.z, m2*v1.z};
            kc[jp] = (f2){lvB*v0.w, lvB*v1.w};
        } else if (MODE == 1) {
            kx[jp] = (f2){-2.f*v0.x, -2.f*v1.x};
            ky[jp] = (f2){-2.f*v0.y, -2.f*v1.y};
            kz[jp] = (f2){-2.f*v0.z, -2.f*v1.z};
            kc[jp] = (f2){v0.w, v1.w};
        } else {
            kx[jp] = (f2){v0.x, v1.x};
            ky[jp] = (f2){v0.y, v1.y};
            kz[jp] = (f2){v0.z, v1.z};
            kc[jp] = (f2){0.f, 0.f};
        }
    }
    __syncthreads();

    float s1[8], s2[8], s3[8];
    if (MODE == 0)      sweep01(pts, kx, ky, kz, kc, t, s1);
    else if (MODE == 1) sweepM(pts, aux, kx, ky, kz, kc, lvA, lvB, t, s1, s2, s3);
    else                sweep3(pts, kx, ky, kz, t, s2);

    __syncthreads();   // staged aux dead -> reuse as reduce scratch

    if (MODE == 1) {
        wave_reduce8(s1, aux, 0, t);
        wave_reduce8(s2, aux, 1, t);
        wave_reduce8(s3, aux, 2, t);
    } else if (MODE == 0) {
        wave_reduce8(s1, aux, 0, t);
    } else {
        wave_reduce8(s2, aux, 0, t);
    }
    __syncthreads();

    const int gi = tile * TILE + t;     // valid t < 32

    if (MODE == 2) {
        if (t < 32) {
            float rs2 = 0.f;
#pragma unroll
            for (int w = 0; w < 8; ++w) rs2 += aux[t*8 + w];
            float v = fmaf(scal[gi], rs2, cost[gi]);
#pragma unroll
            for (int k = 16; k >= 1; k >>= 1) v += __shfl_xor(v, k, 32);
            if (t == 0) atomicAdd(out + b, v);
        }
        return;
    }

    if (t < 32) {
        float rs1 = 0.f, rs2 = 0.f, rs3 = 0.f;
#pragma unroll
        for (int w = 0; w < 8; ++w) rs1 += aux[t*8 + w];
        if (MODE == 1) {
#pragma unroll
            for (int w = 0; w < 8; ++w) rs2 += aux[256 + t*8 + w];
#pragma unroll
            for (int w = 0; w < 8; ++w) rs3 += aux[512 + t*8 + w];
        }
        float scn;
        if (MODE == 0) {
            scn = 1.f / (rs1 + EPS_);                   // satl(0) = 1
        } else {
            const float mysc = scal[gi];                // scale(lev)
            const float sln  = fmaxf(satl[gi] - mysc * rs1, 0.f);
            cost[gi] = fmaf(mysc, rs2, cost[gi]);
            satl[gi] = sln;
            scn = sln / (rs3 + EPS_);                   // scale(lev+1)
        }
        scal[gi] = scn;
        aux[768 + t] = __log2f(scn);                    // broadcast lscale
    }
    __syncthreads();

    // ---- column-partial sweep: cs_j += sum_{my rows} exp2(lvB*d2 + lscale) ----
    f2 kx2[4], ky2[4], kz2[4], kc2[4];
#pragma unroll
    for (int jp = 0; jp < 4; ++jp) {
        float4 v0 = x1v[ob + 2*jp], v1 = x1v[ob + 2*jp + 1];
        const float m2 = -2.f * lvB;
        kx2[jp] = (f2){m2*v0.x, m2*v1.x};
        ky2[jp] = (f2){m2*v0.y, m2*v1.y};
        kz2[jp] = (f2){m2*v0.z, m2*v1.z};
        kc2[jp] = (f2){fmaf(lvB, v0.w, aux[768 + rg*8 + 2*jp]),
                       fmaf(lvB, v1.w, aux[768 + rg*8 + 2*jp + 1])};
    }
    {
        int l = t >> 2;
        float4 p = pts[l];                     // pts untouched since staging
#pragma unroll 2
        for (int i = 0; i < 16; ++i) {
            const int ln = (l + 128) & (N_ - 1);
            const float4 pn = pts[ln];
            const float p2 = fmaf(p.x, p.x, fmaf(p.y, p.y, p.z*p.z));
            const float t2 = lvB * p2;
            const f2 px = (f2){p.x,p.x}, py = (f2){p.y,p.y}, pz = (f2){p.z,p.z};
            const f2 pw = (f2){t2, t2};
            float acc = 0.f;
#pragma unroll
            for (int jp = 0; jp < 4; ++jp) {
                f2 a = kc2[jp] + pw;
                a = kz2[jp] * pz + a;
                a = ky2[jp] * py + a;
                a = kx2[jp] * px + a;
                acc += __builtin_amdgcn_exp2f(a.x) + __builtin_amdgcn_exp2f(a.y);
            }
            acc += __shfl_xor(acc, 1, 64);     // combine 4 row-groups
            acc += __shfl_xor(acc, 2, 64);
            if (rg == 0) atomicAdd(csN + l, acc);
            p = pn; l = ln;
        }
    }
}

extern "C" void kernel_launch(void* const* d_in, const int* in_sizes, int n_in,
                              void* d_out, int out_size, void* d_ws, size_t ws_size,
                              hipStream_t stream)
{
    const float* xyz1 = (const float*)d_in[0];
    const float* xyz2 = (const float*)d_in[1];
    float* out = (float*)d_out;
    float* ws  = (float*)d_ws;

    hipMemsetAsync(d_out, 0, B_ * sizeof(float), stream);
    emd_init<<<BN / 256, 256, 0, stream>>>(xyz1, xyz2, ws);

    static const float levels[11] = {
        -65536.f, -16384.f, -4096.f, -1024.f, -256.f,
        -64.f, -16.f, -4.f, -1.f, -0.25f, 0.f};

    emd_fused<0><<<NBLK, TPB, 0, stream>>>(ws, out, 0.f,
                                           levels[0] * LOG2E, 0);
    for (int lev = 0; lev < 10; ++lev)
        emd_fused<1><<<NBLK, TPB, 0, stream>>>(ws, out,
                                               levels[lev]   * LOG2E,
                                               levels[lev+1] * LOG2E, lev);
    emd_fused<2><<<NBLK, TPB, 0, stream>>>(ws, out, 0.f, 0.f, 10);
}